// Round 9
// baseline (226.663 us; speedup 1.0000x reference)
//
#include <hip/hip_runtime.h>
#include <hip/hip_fp16.h>

typedef _Float16 half8 __attribute__((ext_vector_type(8)));
typedef _Float16 half4 __attribute__((ext_vector_type(4)));
typedef float floatx4 __attribute__((ext_vector_type(4)));

__device__ __forceinline__ void async_ld16(const void* g, void* l) {
    __builtin_amdgcn_global_load_lds(
        (const __attribute__((address_space(1))) char*)g,
        (__attribute__((address_space(3))) char*)l, 16, 0, 0);
}

// fast ELU via HW v_exp_f32; |err| vs expm1f negligible against fp16 rounding.
__device__ __forceinline__ float elu_f(float v) {
    return v > 0.f ? v : (__expf(v) - 1.f);
}

__device__ __forceinline__ half4 cvt4(const float* src, int j4) {
    float4 f = ((const float4*)src)[j4];
    half4 h; h.x = (_Float16)f.x; h.y = (_Float16)f.y;
    h.z = (_Float16)f.z; h.w = (_Float16)f.w; return h;
}

// ---------------------------------------------------------------------------
// K1 convert_all: every fp32 input -> fp16 working buffer (unchanged).
// ---------------------------------------------------------------------------
__launch_bounds__(256)
__global__ void convert_all(const float* __restrict__ x, const float* __restrict__ z,
                            const float* __restrict__ W0, const float* __restrict__ W1,
                            const float* __restrict__ W2, const float* __restrict__ W3,
                            const float* __restrict__ gW1, const float* __restrict__ gW2,
                            const float* __restrict__ gW3,
                            _Float16* __restrict__ X0,
                            _Float16* __restrict__ h0, _Float16* __restrict__ h1,
                            _Float16* __restrict__ h2,
                            _Float16* __restrict__ Wc0, _Float16* __restrict__ Wc1,
                            _Float16* __restrict__ Wc2, _Float16* __restrict__ Wc3,
                            _Float16* __restrict__ gW1c, _Float16* __restrict__ gW2c,
                            _Float16* __restrict__ gW3c)
{
    const int S0 = 294912;                // X0 <- x   (row/72)
    const int S1 = 32768;                 // X0 <- z   (row/8)
    const int S2 = 327680;                // Wc0
    const int S3 = 589824;                // Wc1 <- W1 (row/144, pad)
    const int S4 = 589824;                // Wc2 <- W2
    const int S5 = 98304;                 // Wc3
    const int S6 = 196608;                // h z-cols + pad (3 x 4096 x 16)
    const int S7 = 10240;                 // gW1c
    const int S8 = 4096;                  // gW2c
    const int TOTAL = S0 + S1 + S2 + S3 + S4 + S5 + S6 + S7 + S8 + 256;
    const half4 hz = {};

    for (int i = blockIdx.x * blockDim.x + threadIdx.x; i < TOTAL;
         i += gridDim.x * blockDim.x) {
        int j = i;
        if (j < S0) {
            int r = j / 72, c = j - r * 72;
            *(half4*)(X0 + r * 320 + c * 4) = cvt4(x, j);
            continue;
        }
        j -= S0;
        if (j < S1) {
            int r = j / 8, c = j - r * 8;
            *(half4*)(X0 + r * 320 + 288 + c * 4) = cvt4(z, j);
            continue;
        }
        j -= S1;
        if (j < S2) { *(half4*)(Wc0 + j * 4) = cvt4(W0, j); continue; }
        j -= S2;
        if (j < S3) {
            int r = j / 144, c = j - r * 144;
            *(half4*)(Wc1 + r * 576 + c * 4) = (c < 136) ? cvt4(W1, r * 136 + c) : hz;
            continue;
        }
        j -= S3;
        if (j < S4) {
            int r = j / 144, c = j - r * 144;
            *(half4*)(Wc2 + r * 576 + c * 4) = (c < 136) ? cvt4(W2, r * 136 + c) : hz;
            continue;
        }
        j -= S4;
        if (j < S5) { *(half4*)(Wc3 + j * 4) = cvt4(W3, j); continue; }
        j -= S5;
        if (j < S6) {
            int buf = j >> 16;
            int r2 = j & 65535;
            int row = r2 >> 4, c = r2 & 15;
            _Float16* h = (buf == 0) ? h0 : ((buf == 1) ? h1 : h2);
            *(half4*)(h + row * 576 + 512 + c * 4) = (c < 8) ? cvt4(z, row * 8 + c) : hz;
            continue;
        }
        j -= S6;
        if (j < S7) { *(half4*)(gW1c + j * 4) = cvt4(gW1, j); continue; }
        j -= S7;
        if (j < S8) { *(half4*)(gW2c + j * 4) = cvt4(gW2, j); continue; }
        j -= S8;
        *(half4*)(gW3c + j * 4) = cvt4(gW3, j);
    }
}

// ---------------------------------------------------------------------------
// K2 gating_fast (unchanged — known-good): 64 blocks x 4 waves, each wave
// owns 16 rows, full 3-layer chain + softmax, no __syncthreads.
// ---------------------------------------------------------------------------
__launch_bounds__(256)
__global__ void gating_fast(const _Float16* __restrict__ X0,
                            const _Float16* __restrict__ gW1c,
                            const _Float16* __restrict__ gW2c,
                            const _Float16* __restrict__ gW3c,
                            const float* __restrict__ gb1,
                            const float* __restrict__ gb2,
                            const float* __restrict__ gb3,
                            float* __restrict__ g)
{
    __shared__ _Float16 Tbuf[4 * 16 * 136];   // per-wave [16][136]

    const int tid = threadIdx.x;
    const int l = tid & 63;
    const int w = tid >> 6;
    const int quad = l >> 4;
    const int mi = l & 15;
    const int kq = quad * 8;
    const int mrow = (blockIdx.x * 4 + w) * 16;

    _Float16* T = Tbuf + w * (16 * 136);
    const _Float16* arow = X0 + (size_t)(mrow + mi) * 320;

    floatx4 acc1[8] = {};
    half8 a_nxt = *(const half8*)(arow + kq);
#pragma unroll
    for (int kc = 0; kc < 10; kc++) {
        const int k0 = kc * 32;
        half8 a = a_nxt;
        if (kc < 9) a_nxt = *(const half8*)(arow + k0 + 32 + kq);
#pragma unroll
        for (int t = 0; t < 8; t++) {
            half8 b = *(const half8*)(gW1c + (size_t)(t * 16 + mi) * 320 + k0 + kq);
            acc1[t] = __builtin_amdgcn_mfma_f32_16x16x32_f16(a, b, acc1[t], 0, 0, 0);
        }
    }
#pragma unroll
    for (int t = 0; t < 8; t++) {
        const int n = t * 16 + mi;
        const float bn = gb1[n];
#pragma unroll
        for (int r = 0; r < 4; r++)
            T[(quad * 4 + r) * 136 + n] = (_Float16)elu_f(acc1[t][r] + bn);
    }

    floatx4 acc2[8] = {};
#pragma unroll
    for (int kc = 0; kc < 4; kc++) {
        const int k0 = kc * 32;
        half8 a = *(const half8*)(T + mi * 136 + k0 + kq);
#pragma unroll
        for (int t = 0; t < 8; t++) {
            half8 b = *(const half8*)(gW2c + (size_t)(t * 16 + mi) * 128 + k0 + kq);
            acc2[t] = __builtin_amdgcn_mfma_f32_16x16x32_f16(a, b, acc2[t], 0, 0, 0);
        }
    }
#pragma unroll
    for (int t = 0; t < 8; t++) {
        const int n = t * 16 + mi;
        const float bn = gb2[n];
#pragma unroll
        for (int r = 0; r < 4; r++)
            T[(quad * 4 + r) * 136 + n] = (_Float16)elu_f(acc2[t][r] + bn);
    }

    floatx4 acc3 = {};
#pragma unroll
    for (int kc = 0; kc < 4; kc++) {
        const int k0 = kc * 32;
        half8 a = *(const half8*)(T + mi * 136 + k0 + kq);
        half8 b = (mi < 8) ? *(const half8*)(gW3c + (size_t)mi * 128 + k0 + kq) : half8{};
        acc3 = __builtin_amdgcn_mfma_f32_16x16x32_f16(a, b, acc3, 0, 0, 0);
    }
    const float gb = gb3[mi & 7];
#pragma unroll
    for (int r = 0; r < 4; r++) {
        float logit = acc3[r] + gb;
        float mx = logit;
        mx = fmaxf(mx, __shfl_xor(mx, 1));
        mx = fmaxf(mx, __shfl_xor(mx, 2));
        mx = fmaxf(mx, __shfl_xor(mx, 4));
        float e = __expf(logit - mx);
        float s = e;
        s += __shfl_xor(s, 1);
        s += __shfl_xor(s, 2);
        s += __shfl_xor(s, 4);
        if (mi < 8)
            g[(size_t)(mrow + quad * 4 + r) * 8 + mi] = e / s;
    }
}

// ---------------------------------------------------------------------------
// blend64 (r7 structure): BK=64, XOR-swizzled LDS, XCD swizzle optional.
// CHANGE: __launch_bounds__(256, 3) — the wave needs ~132 unified regs
// (64 arch VGPR + 64 AGPR acc + frags); the old (256,4) capped at 128,
// risking scratch spills in the K-loop (suspected cause of the ~43 µs/layer
// latency plateau). (256,3) caps at 170 — no spill possible, 12 waves/CU.
// SHADOW instrumentation: if blockIdx.x >= 1024, recompute the same tile
// (id & 1023) and write to outS — identical work, doubles the dispatch
// duration so it tops the rocprof profile over the 44 µs harness fills.
// ---------------------------------------------------------------------------
template <bool ELU_ACT, bool SWZ, typename OUT_T>
__launch_bounds__(256, 3)
__global__ void blend64(const _Float16* __restrict__ A, int lda,
                        const _Float16* __restrict__ W, int ldw,
                        int Hdim, int K,
                        const float* __restrict__ g,
                        const float* __restrict__ bias,
                        OUT_T* __restrict__ out,
                        OUT_T* __restrict__ outS, int ldo)
{
    __shared__ __align__(16) char smem_raw[32768];
    _Float16* sA = (_Float16*)smem_raw;            // [128][64]
    _Float16* sB = (_Float16*)(smem_raw + 16384);  // [128][64]
    float* sredf = (float*)smem_raw;               // [2][64][17] overlay (epilogue)
    __shared__ float sg[128][9];
    __shared__ float sbias[8][16];

    const int tid = threadIdx.x;
    const int l = tid & 63;
    const int w = tid >> 6;
    const int wm = w >> 1, wn = w & 1;

    const bool shadow = (blockIdx.x >= 1024);
    OUT_T* const outp = shadow ? outS : out;

    int by, bx;
    if (SWZ) {
        const int id = blockIdx.x & 1023;
        const int r = id & 7, q = id >> 3;
        by = (r >> 1) * 8 + (q & 7);
        bx = (r & 1) * 16 + (q >> 3);
    } else {
        const int id = blockIdx.x;
        by = id / 6;
        bx = id - by * 6;
    }
    const int o0 = bx * 16;
    const int m0 = by * 128;

    for (int t = tid; t < 128 * 8; t += 256)
        sg[t >> 3][t & 7] = g[(size_t)(m0 + (t >> 3)) * 8 + (t & 7)];
    for (int t = tid; t < 128; t += 256)
        sbias[t >> 4][t & 15] = bias[(t >> 4) * Hdim + o0 + (t & 15)];

    const int lr = l >> 3;
    const int lc = l & 7;
    const int swz = lc ^ lr;

    const _Float16* gAp = A + (size_t)(m0 + w * 64 + lr) * lda + swz * 8;
    _Float16* lAp = sA + w * 4096;
    const int wb = w - 2;
    const int eb = wb * 4;
    const _Float16* gBe = W + ((size_t)eb * Hdim + o0 + lr) * ldw + swz * 8;
    const _Float16* gBo = gBe + (size_t)8 * ldw;
    _Float16* lBp = sB + wb * 4096;

    const int mi = l & 15, quad = l >> 4;
    const int cswz = mi & 7;
    const int offh0 = ((quad ^ cswz) * 8);
    const int offh1 = (((quad + 4) ^ cswz) * 8);
    const _Float16* rAb = sA + (wm * 64 + mi) * 64;
    const _Float16* rBb = sB + (wn * 64 + mi) * 64;

    floatx4 acc[4][4] = {};

    for (int k0 = 0; k0 < K; k0 += 64) {
        __syncthreads();
        if (w < 2) {
            const _Float16* gp = gAp + k0;
            _Float16* lp = lAp;
#pragma unroll
            for (int c = 0; c < 8; c++) {
                async_ld16(gp, lp);
                gp += (size_t)8 * lda;
                lp += 512;
            }
        } else {
            const _Float16* ge = gBe + k0;
            const _Float16* go = gBo + k0;
            _Float16* lp = lBp;
#pragma unroll
            for (int c2 = 0; c2 < 4; c2++) {
                async_ld16(ge, lp); lp += 512;
                async_ld16(go, lp); lp += 512;
                ge += (size_t)Hdim * ldw;
                go += (size_t)Hdim * ldw;
            }
        }
        __syncthreads();
#pragma unroll
        for (int h = 0; h < 2; h++) {
            const int off = h ? offh1 : offh0;
            half8 af[4], bf[4];
#pragma unroll
            for (int i = 0; i < 4; i++) af[i] = *(const half8*)(rAb + i * 1024 + off);
#pragma unroll
            for (int j = 0; j < 4; j++) bf[j] = *(const half8*)(rBb + j * 1024 + off);
#pragma unroll
            for (int i = 0; i < 4; i++)
#pragma unroll
                for (int j = 0; j < 4; j++)
                    acc[i][j] = __builtin_amdgcn_mfma_f32_16x16x32_f16(af[i], bf[j], acc[i][j], 0, 0, 0);
        }
    }

    float p[4][4];
#pragma unroll
    for (int i = 0; i < 4; i++)
#pragma unroll
        for (int r = 0; r < 4; r++) {
            int mloc = wm * 64 + i * 16 + quad * 4 + r;
            float s = 0.f;
#pragma unroll
            for (int j = 0; j < 4; j++) {
                int e = wn * 4 + j;
                s += sg[mloc][e] * (acc[i][j][r] + sbias[e][mi]);
            }
            p[i][r] = s;
        }

    __syncthreads();
    if (wn == 0) {
#pragma unroll
        for (int i = 0; i < 4; i++)
#pragma unroll
            for (int r = 0; r < 4; r++)
                sredf[(wm * 64 + i * 16 + quad * 4 + r) * 17 + mi] = p[i][r];
    }
    __syncthreads();
    if (wn == 1) {
#pragma unroll
        for (int i = 0; i < 4; i++)
#pragma unroll
            for (int r = 0; r < 4; r++) {
                int mrel = i * 16 + quad * 4 + r;
                float v = p[i][r] + sredf[(wm * 64 + mrel) * 17 + mi];
                if (ELU_ACT) v = elu_f(v);
                outp[(size_t)(m0 + wm * 64 + mrel) * ldo + o0 + mi] = (OUT_T)v;
            }
    }
}

// ---------------------------------------------------------------------------
extern "C" void kernel_launch(void* const* d_in, const int* in_sizes, int n_in,
                              void* d_out, int out_size, void* d_ws, size_t ws_size,
                              hipStream_t stream)
{
    (void)in_sizes; (void)n_in; (void)out_size; (void)ws_size;
    const float* x   = (const float*)d_in[0];
    const float* z   = (const float*)d_in[1];
    const float* W0  = (const float*)d_in[2];
    const float* b0  = (const float*)d_in[3];
    const float* W1  = (const float*)d_in[4];
    const float* b1  = (const float*)d_in[5];
    const float* W2  = (const float*)d_in[6];
    const float* b2  = (const float*)d_in[7];
    const float* W3  = (const float*)d_in[8];
    const float* b3  = (const float*)d_in[9];
    const float* gW1 = (const float*)d_in[10];
    const float* gb1 = (const float*)d_in[11];
    const float* gW2 = (const float*)d_in[12];
    const float* gb2 = (const float*)d_in[13];
    const float* gW3 = (const float*)d_in[14];
    const float* gb3 = (const float*)d_in[15];

    char* p = (char*)d_ws;
    auto alloc = [&](size_t n) { char* r = p; p += (n + 255) & ~(size_t)255; return r; };
    _Float16* X0   = (_Float16*)alloc((size_t)4096 * 320 * 2);
    _Float16* h0   = (_Float16*)alloc((size_t)4096 * 576 * 2);
    _Float16* h1   = (_Float16*)alloc((size_t)4096 * 576 * 2);
    _Float16* h2   = (_Float16*)alloc((size_t)4096 * 576 * 2);
    _Float16* hsh  = (_Float16*)alloc((size_t)4096 * 576 * 2);   // shadow (instr.)
    _Float16* Wc0  = (_Float16*)alloc((size_t)8 * 512 * 320 * 2);
    _Float16* Wc1  = (_Float16*)alloc((size_t)8 * 512 * 576 * 2);
    _Float16* Wc2  = (_Float16*)alloc((size_t)8 * 512 * 576 * 2);
    _Float16* Wc3  = (_Float16*)alloc((size_t)8 * 96 * 512 * 2);
    _Float16* gW1c = (_Float16*)alloc((size_t)128 * 320 * 2);
    _Float16* gW2c = (_Float16*)alloc((size_t)128 * 128 * 2);
    _Float16* gW3c = (_Float16*)alloc((size_t)8 * 128 * 2);
    float*    g    = (float*)alloc((size_t)4096 * 8 * 4);

    convert_all<<<1024, 256, 0, stream>>>(x, z, W0, W1, W2, W3, gW1, gW2, gW3,
                                          X0, h0, h1, h2, Wc0, Wc1, Wc2, Wc3,
                                          gW1c, gW2c, gW3c);

    gating_fast<<<64, 256, 0, stream>>>(X0, gW1c, gW2c, gW3c, gb1, gb2, gb3, g);

    blend64<true, true, _Float16><<<1024, 256, 0, stream>>>(X0, 320, Wc0, 320, 512, 320, g, b0, h0, h0, 576);
    // layer 1: 2x grid — upper half recomputes into hsh (pure instrumentation)
    blend64<true, true, _Float16><<<2048, 256, 0, stream>>>(h0, 576, Wc1, 576, 512, 576, g, b1, h1, hsh, 576);
    blend64<true, true, _Float16><<<1024, 256, 0, stream>>>(h1, 576, Wc2, 576, 512, 576, g, b2, h2, h2, 576);
    blend64<false, false, float><<<192, 256, 0, stream>>>(h2, 576, Wc3, 512, 96, 512, g, b3, (float*)d_out, (float*)d_out, 96);
}

// Round 10
// 189.134 us; speedup vs baseline: 1.1984x; 1.1984x over previous
//
#include <hip/hip_runtime.h>
#include <hip/hip_fp16.h>

typedef _Float16 half8 __attribute__((ext_vector_type(8)));
typedef _Float16 half4 __attribute__((ext_vector_type(4)));
typedef float floatx4 __attribute__((ext_vector_type(4)));

__device__ __forceinline__ void async_ld16(const void* g, void* l) {
    __builtin_amdgcn_global_load_lds(
        (const __attribute__((address_space(1))) char*)g,
        (__attribute__((address_space(3))) char*)l, 16, 0, 0);
}

// fast ELU via HW v_exp_f32; |err| vs expm1f negligible against fp16 rounding.
__device__ __forceinline__ float elu_f(float v) {
    return v > 0.f ? v : (__expf(v) - 1.f);
}

__device__ __forceinline__ half4 cvt4(const float* src, int j4) {
    float4 f = ((const float4*)src)[j4];
    half4 h; h.x = (_Float16)f.x; h.y = (_Float16)f.y;
    h.z = (_Float16)f.z; h.w = (_Float16)f.w; return h;
}

// ---------------------------------------------------------------------------
// K1 convert_all: every fp32 input -> fp16 working buffer (unchanged).
// ---------------------------------------------------------------------------
__launch_bounds__(256)
__global__ void convert_all(const float* __restrict__ x, const float* __restrict__ z,
                            const float* __restrict__ W0, const float* __restrict__ W1,
                            const float* __restrict__ W2, const float* __restrict__ W3,
                            const float* __restrict__ gW1, const float* __restrict__ gW2,
                            const float* __restrict__ gW3,
                            _Float16* __restrict__ X0,
                            _Float16* __restrict__ h0, _Float16* __restrict__ h1,
                            _Float16* __restrict__ h2,
                            _Float16* __restrict__ Wc0, _Float16* __restrict__ Wc1,
                            _Float16* __restrict__ Wc2, _Float16* __restrict__ Wc3,
                            _Float16* __restrict__ gW1c, _Float16* __restrict__ gW2c,
                            _Float16* __restrict__ gW3c)
{
    const int S0 = 294912;                // X0 <- x   (row/72)
    const int S1 = 32768;                 // X0 <- z   (row/8)
    const int S2 = 327680;                // Wc0
    const int S3 = 589824;                // Wc1 <- W1 (row/144, pad)
    const int S4 = 589824;                // Wc2 <- W2
    const int S5 = 98304;                 // Wc3
    const int S6 = 196608;                // h z-cols + pad (3 x 4096 x 16)
    const int S7 = 10240;                 // gW1c
    const int S8 = 4096;                  // gW2c
    const int TOTAL = S0 + S1 + S2 + S3 + S4 + S5 + S6 + S7 + S8 + 256;
    const half4 hz = {};

    for (int i = blockIdx.x * blockDim.x + threadIdx.x; i < TOTAL;
         i += gridDim.x * blockDim.x) {
        int j = i;
        if (j < S0) {
            int r = j / 72, c = j - r * 72;
            *(half4*)(X0 + r * 320 + c * 4) = cvt4(x, j);
            continue;
        }
        j -= S0;
        if (j < S1) {
            int r = j / 8, c = j - r * 8;
            *(half4*)(X0 + r * 320 + 288 + c * 4) = cvt4(z, j);
            continue;
        }
        j -= S1;
        if (j < S2) { *(half4*)(Wc0 + j * 4) = cvt4(W0, j); continue; }
        j -= S2;
        if (j < S3) {
            int r = j / 144, c = j - r * 144;
            *(half4*)(Wc1 + r * 576 + c * 4) = (c < 136) ? cvt4(W1, r * 136 + c) : hz;
            continue;
        }
        j -= S3;
        if (j < S4) {
            int r = j / 144, c = j - r * 144;
            *(half4*)(Wc2 + r * 576 + c * 4) = (c < 136) ? cvt4(W2, r * 136 + c) : hz;
            continue;
        }
        j -= S4;
        if (j < S5) { *(half4*)(Wc3 + j * 4) = cvt4(W3, j); continue; }
        j -= S5;
        if (j < S6) {
            int buf = j >> 16;
            int r2 = j & 65535;
            int row = r2 >> 4, c = r2 & 15;
            _Float16* h = (buf == 0) ? h0 : ((buf == 1) ? h1 : h2);
            *(half4*)(h + row * 576 + 512 + c * 4) = (c < 8) ? cvt4(z, row * 8 + c) : hz;
            continue;
        }
        j -= S6;
        if (j < S7) { *(half4*)(gW1c + j * 4) = cvt4(gW1, j); continue; }
        j -= S7;
        if (j < S8) { *(half4*)(gW2c + j * 4) = cvt4(gW2, j); continue; }
        j -= S8;
        *(half4*)(gW3c + j * 4) = cvt4(gW3, j);
    }
}

// ---------------------------------------------------------------------------
// K2 gating_fast (unchanged — known-good): 64 blocks x 4 waves, each wave
// owns 16 rows, full 3-layer chain + softmax, no __syncthreads.
// ---------------------------------------------------------------------------
__launch_bounds__(256)
__global__ void gating_fast(const _Float16* __restrict__ X0,
                            const _Float16* __restrict__ gW1c,
                            const _Float16* __restrict__ gW2c,
                            const _Float16* __restrict__ gW3c,
                            const float* __restrict__ gb1,
                            const float* __restrict__ gb2,
                            const float* __restrict__ gb3,
                            float* __restrict__ g)
{
    __shared__ _Float16 Tbuf[4 * 16 * 136];   // per-wave [16][136]

    const int tid = threadIdx.x;
    const int l = tid & 63;
    const int w = tid >> 6;
    const int quad = l >> 4;
    const int mi = l & 15;
    const int kq = quad * 8;
    const int mrow = (blockIdx.x * 4 + w) * 16;

    _Float16* T = Tbuf + w * (16 * 136);
    const _Float16* arow = X0 + (size_t)(mrow + mi) * 320;

    floatx4 acc1[8] = {};
    half8 a_nxt = *(const half8*)(arow + kq);
#pragma unroll
    for (int kc = 0; kc < 10; kc++) {
        const int k0 = kc * 32;
        half8 a = a_nxt;
        if (kc < 9) a_nxt = *(const half8*)(arow + k0 + 32 + kq);
#pragma unroll
        for (int t = 0; t < 8; t++) {
            half8 b = *(const half8*)(gW1c + (size_t)(t * 16 + mi) * 320 + k0 + kq);
            acc1[t] = __builtin_amdgcn_mfma_f32_16x16x32_f16(a, b, acc1[t], 0, 0, 0);
        }
    }
#pragma unroll
    for (int t = 0; t < 8; t++) {
        const int n = t * 16 + mi;
        const float bn = gb1[n];
#pragma unroll
        for (int r = 0; r < 4; r++)
            T[(quad * 4 + r) * 136 + n] = (_Float16)elu_f(acc1[t][r] + bn);
    }

    floatx4 acc2[8] = {};
#pragma unroll
    for (int kc = 0; kc < 4; kc++) {
        const int k0 = kc * 32;
        half8 a = *(const half8*)(T + mi * 136 + k0 + kq);
#pragma unroll
        for (int t = 0; t < 8; t++) {
            half8 b = *(const half8*)(gW2c + (size_t)(t * 16 + mi) * 128 + k0 + kq);
            acc2[t] = __builtin_amdgcn_mfma_f32_16x16x32_f16(a, b, acc2[t], 0, 0, 0);
        }
    }
#pragma unroll
    for (int t = 0; t < 8; t++) {
        const int n = t * 16 + mi;
        const float bn = gb2[n];
#pragma unroll
        for (int r = 0; r < 4; r++)
            T[(quad * 4 + r) * 136 + n] = (_Float16)elu_f(acc2[t][r] + bn);
    }

    floatx4 acc3 = {};
#pragma unroll
    for (int kc = 0; kc < 4; kc++) {
        const int k0 = kc * 32;
        half8 a = *(const half8*)(T + mi * 136 + k0 + kq);
        half8 b = (mi < 8) ? *(const half8*)(gW3c + (size_t)mi * 128 + k0 + kq) : half8{};
        acc3 = __builtin_amdgcn_mfma_f32_16x16x32_f16(a, b, acc3, 0, 0, 0);
    }
    const float gb = gb3[mi & 7];
#pragma unroll
    for (int r = 0; r < 4; r++) {
        float logit = acc3[r] + gb;
        float mx = logit;
        mx = fmaxf(mx, __shfl_xor(mx, 1));
        mx = fmaxf(mx, __shfl_xor(mx, 2));
        mx = fmaxf(mx, __shfl_xor(mx, 4));
        float e = __expf(logit - mx);
        float s = e;
        s += __shfl_xor(s, 1);
        s += __shfl_xor(s, 2);
        s += __shfl_xor(s, 4);
        if (mi < 8)
            g[(size_t)(mrow + quad * 4 + r) * 8 + mi] = e / s;
    }
}

// ---------------------------------------------------------------------------
// blend256: 256x128 tile, 512 threads = 8 waves (wm=w>>1 over 4x64 rows,
// wn=w&1 over 2x64 tile-cols) — each wave runs the byte-identical proven
// 64x64 fragment pattern. Staging/iter = A 32 KB + B 16 KB = 48 KB for 2x
// the FLOPs of the 128x128 tile -> 0.72x staged bytes/layer (BW-bound fix).
// __launch_bounds__(512,4): 128 unified regs/wave -> 2 blocks/CU (16 waves,
// same latency hiding as before). sg stored fp16 (err <= 2e-5). XOR-swizzled
// 16B chunks as before. Epilogue: wn-pair reduce, sred overlays dead sA.
// SWZ: per-XCD region = 4 by x 16 bx -> 3.5 MB working set < 4 MB L2.
// ---------------------------------------------------------------------------
template <bool ELU_ACT, bool SWZ, typename OUT_T>
__launch_bounds__(512, 4)
__global__ void blend256(const _Float16* __restrict__ A, int lda,
                         const _Float16* __restrict__ W, int ldw,
                         int Hdim, int K,
                         const float* __restrict__ g,
                         const float* __restrict__ bias,
                         OUT_T* __restrict__ out, int ldo)
{
    __shared__ __align__(16) char smem_raw[49152];
    _Float16* sA = (_Float16*)smem_raw;            // [256][64]  32 KB
    _Float16* sB = (_Float16*)(smem_raw + 32768);  // [128][64]  16 KB
    float* sredf = (float*)smem_raw;               // [256][17] fp32 overlay (epilogue)
    __shared__ _Float16 sg[256][8];
    __shared__ float sbias[8][16];

    const int tid = threadIdx.x;
    const int l = tid & 63;
    const int w = tid >> 6;            // 0..7
    const int wm = w >> 1, wn = w & 1;

    int by, bx;
    if (SWZ) {
        const int id = blockIdx.x;     // 512 blocks
        const int r = id & 7, q = id >> 3;       // q: 0..63
        by = (r >> 1) * 4 + (q & 3);             // 0..15
        bx = (r & 1) * 16 + (q >> 2);            // 0..31
    } else {
        const int id = blockIdx.x;
        by = id / 6;
        bx = id - by * 6;
    }
    const int o0 = bx * 16;
    const int m0 = by * 256;

    for (int t = tid; t < 256 * 8; t += 512)
        sg[t >> 3][t & 7] = (_Float16)g[(size_t)(m0 + (t >> 3)) * 8 + (t & 7)];
    if (tid < 128)
        sbias[tid >> 4][tid & 15] = bias[(tid >> 4) * Hdim + o0 + (tid & 15)];

    // staging: lr = row-in-group, lc = dest chunk, swz = src chunk (XOR)
    const int lr = l >> 3;
    const int lc = l & 7;
    const int swz = lc ^ lr;

    // A: wave w stages row-groups w*4+c (c=0..3): rows w*32 + c*8 + lr
    const _Float16* gAp = A + (size_t)(m0 + w * 32 + lr) * lda + swz * 8;
    _Float16* const lAp = sA + w * 2048;           // 4 groups x 512 elems
    // B: wave w stages col-groups w*2+c (c=0..1): tile-cols w*16 + c*8 + lr
    //    tile-col = e*16+oc with e = w, oc = c*8+lr
    const _Float16* gBp = W + ((size_t)w * Hdim + o0 + lr) * ldw + swz * 8;
    _Float16* const lBp = sB + w * 1024;           // 2 groups x 512 elems

    // fragment read pointers
    const int mi = l & 15, quad = l >> 4;
    const int cswz = mi & 7;
    const _Float16* const rAb = sA + (wm * 64 + mi) * 64;
    const _Float16* const rBb = sB + (wn * 64 + mi) * 64;

    floatx4 acc[4][4] = {};

    for (int k0 = 0; k0 < K; k0 += 64) {
        __syncthreads();
        {
            const _Float16* ga = gAp + k0;
#pragma unroll
            for (int c = 0; c < 4; c++)
                async_ld16(ga + (size_t)c * 8 * lda, lAp + c * 512);
            const _Float16* gb = gBp + k0;
#pragma unroll
            for (int c = 0; c < 2; c++)
                async_ld16(gb + (size_t)c * 8 * ldw, lBp + c * 512);
        }
        __syncthreads();
#pragma unroll
        for (int h = 0; h < 2; h++) {
            const int off = ((h * 4 + quad) ^ cswz) * 8;
            half8 af[4], bf[4];
#pragma unroll
            for (int i = 0; i < 4; i++) af[i] = *(const half8*)(rAb + i * 1024 + off);
#pragma unroll
            for (int j = 0; j < 4; j++) bf[j] = *(const half8*)(rBb + j * 1024 + off);
#pragma unroll
            for (int i = 0; i < 4; i++)
#pragma unroll
                for (int j = 0; j < 4; j++)
                    acc[i][j] = __builtin_amdgcn_mfma_f32_16x16x32_f16(af[i], bf[j], acc[i][j], 0, 0, 0);
        }
    }

    // blend: wave's expert for col-tile j is e = wn*4 + j; out col = o0 + mi
    float p[4][4];
#pragma unroll
    for (int i = 0; i < 4; i++)
#pragma unroll
        for (int r = 0; r < 4; r++) {
            const int mloc = wm * 64 + i * 16 + quad * 4 + r;
            float s = 0.f;
#pragma unroll
            for (int j = 0; j < 4; j++) {
                const int e = wn * 4 + j;
                s += (float)sg[mloc][e] * (acc[i][j][r] + sbias[e][mi]);
            }
            p[i][r] = s;
        }

    __syncthreads();   // staging LDS dead; overlay sred [256][17]
    if (wn == 0) {
#pragma unroll
        for (int i = 0; i < 4; i++)
#pragma unroll
            for (int r = 0; r < 4; r++)
                sredf[(wm * 64 + i * 16 + quad * 4 + r) * 17 + mi] = p[i][r];
    }
    __syncthreads();
    if (wn == 1) {
#pragma unroll
        for (int i = 0; i < 4; i++)
#pragma unroll
            for (int r = 0; r < 4; r++) {
                const int mrel = wm * 64 + i * 16 + quad * 4 + r;
                float v = p[i][r] + sredf[mrel * 17 + mi];
                if (ELU_ACT) v = elu_f(v);
                out[(size_t)(m0 + mrel) * ldo + o0 + mi] = (OUT_T)v;
            }
    }
}

// ---------------------------------------------------------------------------
extern "C" void kernel_launch(void* const* d_in, const int* in_sizes, int n_in,
                              void* d_out, int out_size, void* d_ws, size_t ws_size,
                              hipStream_t stream)
{
    (void)in_sizes; (void)n_in; (void)out_size; (void)ws_size;
    const float* x   = (const float*)d_in[0];
    const float* z   = (const float*)d_in[1];
    const float* W0  = (const float*)d_in[2];
    const float* b0  = (const float*)d_in[3];
    const float* W1  = (const float*)d_in[4];
    const float* b1  = (const float*)d_in[5];
    const float* W2  = (const float*)d_in[6];
    const float* b2  = (const float*)d_in[7];
    const float* W3  = (const float*)d_in[8];
    const float* b3  = (const float*)d_in[9];
    const float* gW1 = (const float*)d_in[10];
    const float* gb1 = (const float*)d_in[11];
    const float* gW2 = (const float*)d_in[12];
    const float* gb2 = (const float*)d_in[13];
    const float* gW3 = (const float*)d_in[14];
    const float* gb3 = (const float*)d_in[15];

    char* p = (char*)d_ws;
    auto alloc = [&](size_t n) { char* r = p; p += (n + 255) & ~(size_t)255; return r; };
    _Float16* X0   = (_Float16*)alloc((size_t)4096 * 320 * 2);
    _Float16* h0   = (_Float16*)alloc((size_t)4096 * 576 * 2);
    _Float16* h1   = (_Float16*)alloc((size_t)4096 * 576 * 2);
    _Float16* h2   = (_Float16*)alloc((size_t)4096 * 576 * 2);
    _Float16* Wc0  = (_Float16*)alloc((size_t)8 * 512 * 320 * 2);
    _Float16* Wc1  = (_Float16*)alloc((size_t)8 * 512 * 576 * 2);
    _Float16* Wc2  = (_Float16*)alloc((size_t)8 * 512 * 576 * 2);
    _Float16* Wc3  = (_Float16*)alloc((size_t)8 * 96 * 512 * 2);
    _Float16* gW1c = (_Float16*)alloc((size_t)128 * 320 * 2);
    _Float16* gW2c = (_Float16*)alloc((size_t)128 * 128 * 2);
    _Float16* gW3c = (_Float16*)alloc((size_t)8 * 128 * 2);
    float*    g    = (float*)alloc((size_t)4096 * 8 * 4);

    convert_all<<<1024, 256, 0, stream>>>(x, z, W0, W1, W2, W3, gW1, gW2, gW3,
                                          X0, h0, h1, h2, Wc0, Wc1, Wc2, Wc3,
                                          gW1c, gW2c, gW3c);

    gating_fast<<<64, 256, 0, stream>>>(X0, gW1c, gW2c, gW3c, gb1, gb2, gb3, g);

    blend256<true, true, _Float16><<<512, 512, 0, stream>>>(X0, 320, Wc0, 320, 512, 320, g, b0, h0, 576);
    blend256<true, true, _Float16><<<512, 512, 0, stream>>>(h0, 576, Wc1, 576, 512, 576, g, b1, h1, 576);
    blend256<true, true, _Float16><<<512, 512, 0, stream>>>(h1, 576, Wc2, 576, 512, 576, g, b2, h2, 576);
    blend256<false, false, float><<<96, 512, 0, stream>>>(h2, 576, Wc3, 512, 96, 512, g, b3, (float*)d_out, 96);
}